// Round 4
// baseline (729.937 us; speedup 1.0000x reference)
//
#include <hip/hip_runtime.h>
#include <math.h>

#define N_NODES 20000
#define E_EDGES 320000
#define NHEADS 4
#define RMIN 2.2e-10f
#define THETA_MAX 1000.0f
#define SLOPE 0.2f

__device__ __forceinline__ float softplus_f(float x) {
    return fmaxf(x, 0.0f) + log1pf(expf(-fabsf(x)));
}

// ---------------- CSR build ----------------
__global__ __launch_bounds__(256) void count_kernel(const int* __restrict__ dst,
                                                    int* __restrict__ deg) {
    int e = blockIdx.x * 256 + threadIdx.x;
    if (e < E_EDGES) atomicAdd(&deg[dst[e]], 1);
}

__global__ __launch_bounds__(256) void scan_kernel(const int* __restrict__ deg,
                                                   int* __restrict__ rowptr,
                                                   int* __restrict__ cursor) {
    __shared__ int part[256];
    int t = threadIdx.x;
    const int CH = (N_NODES + 255) / 256;
    int base = t * CH;
    int sum = 0;
    for (int i = 0; i < CH; ++i) {
        int idx = base + i;
        if (idx < N_NODES) sum += deg[idx];
    }
    part[t] = sum;
    __syncthreads();
    for (int off = 1; off < 256; off <<= 1) {
        int v = (t >= off) ? part[t - off] : 0;
        __syncthreads();
        part[t] += v;
        __syncthreads();
    }
    int run = (t == 0) ? 0 : part[t - 1];
    for (int i = 0; i < CH; ++i) {
        int idx = base + i;
        if (idx < N_NODES) {
            rowptr[idx] = run;
            cursor[idx] = run;
            run += deg[idx];
        }
    }
    if (t == 255) rowptr[N_NODES] = run;
}

__global__ __launch_bounds__(256) void scatter_kernel(const int* __restrict__ src,
                                                      const int* __restrict__ dst,
                                                      int* __restrict__ cursor,
                                                      int* __restrict__ csr) {
    int e = blockIdx.x * 256 + threadIdx.x;
    if (e < E_EDGES) {
        int p = atomicAdd(&cursor[dst[e]], 1);
        csr[p] = src[e];
    }
}

// ---------------- GEMM: out[M,NO] = A[M,K]*W[NO,K]^T, 128xBN tile, 8x(BN/16)/thread ----
// MODE: 0 raw, 1 softplus(v+b), 2 clip(softplus,0.1,1000), 3 max(softplus,RMIN)
template <int MODE, bool TRANS, int BN>
__global__ __launch_bounds__(256) void gemm_big(const float* __restrict__ A,
                                                const float* __restrict__ W,
                                                const float* __restrict__ bias,
                                                float* __restrict__ out,
                                                int M, int K, int NO) {
    constexpr int TN = BN / 16;
    __shared__ float As[16][132];
    __shared__ float Bs[16][BN + 4];
    int tid = threadIdx.x;
    int tx = tid & 15, ty = tid >> 4;
    int bm = blockIdx.x * 128;
    int bn = blockIdx.y * BN;
    float acc[8][TN] = {};

    int am = tid >> 1;
    int ak = (tid & 1) * 8;
    int arow = bm + am;
    bool aval = arow < M;
    const float* Arow = A + (size_t)arow * K + ak;

    int bo, bk;
    if (BN == 128) { bo = tid >> 1; bk = (tid & 1) * 8; }
    else           { bo = tid >> 2; bk = (tid & 3) * 4; }
    const float* Wrow = W + (size_t)(bn + bo) * K + bk;

    for (int k0 = 0; k0 < K; k0 += 16) {
        float4 a0 = make_float4(0.f, 0.f, 0.f, 0.f), a1 = a0;
        if (aval) {
            a0 = *(const float4*)(Arow + k0);
            a1 = *(const float4*)(Arow + k0 + 4);
        }
        As[ak + 0][am] = a0.x; As[ak + 1][am] = a0.y;
        As[ak + 2][am] = a0.z; As[ak + 3][am] = a0.w;
        As[ak + 4][am] = a1.x; As[ak + 5][am] = a1.y;
        As[ak + 6][am] = a1.z; As[ak + 7][am] = a1.w;
        if (BN == 128) {
            float4 b0 = *(const float4*)(Wrow + k0);
            float4 b1 = *(const float4*)(Wrow + k0 + 4);
            Bs[bk + 0][bo] = b0.x; Bs[bk + 1][bo] = b0.y;
            Bs[bk + 2][bo] = b0.z; Bs[bk + 3][bo] = b0.w;
            Bs[bk + 4][bo] = b1.x; Bs[bk + 5][bo] = b1.y;
            Bs[bk + 6][bo] = b1.z; Bs[bk + 7][bo] = b1.w;
        } else {
            float4 b0 = *(const float4*)(Wrow + k0);
            Bs[bk + 0][bo] = b0.x; Bs[bk + 1][bo] = b0.y;
            Bs[bk + 2][bo] = b0.z; Bs[bk + 3][bo] = b0.w;
        }
        __syncthreads();
#pragma unroll
        for (int kk = 0; kk < 16; ++kk) {
            float a[8], b[TN];
            *(float4*)(a) = *(const float4*)(&As[kk][ty * 8]);
            *(float4*)(a + 4) = *(const float4*)(&As[kk][ty * 8 + 4]);
            *(float4*)(b) = *(const float4*)(&Bs[kk][tx * TN]);
            if (TN == 8) *(float4*)(b + 4) = *(const float4*)(&Bs[kk][tx * TN + 4]);
#pragma unroll
            for (int i = 0; i < 8; ++i)
#pragma unroll
                for (int j = 0; j < TN; ++j) acc[i][j] += a[i] * b[j];
        }
        __syncthreads();
    }

    int r0 = bm + ty * 8;
    int c0 = bn + tx * TN;
    float bv[TN];
#pragma unroll
    for (int j = 0; j < TN; ++j) bv[j] = 0.f;
    if (MODE != 0) {
        *(float4*)(bv) = *(const float4*)(bias + c0);
        if (TN == 8) *(float4*)(bv + 4) = *(const float4*)(bias + c0 + 4);
    }
    float vals[8][TN];
#pragma unroll
    for (int i = 0; i < 8; ++i)
#pragma unroll
        for (int j = 0; j < TN; ++j) {
            float v = acc[i][j];
            if (MODE == 1) v = softplus_f(v + bv[j]);
            else if (MODE == 2) { v = softplus_f(v + bv[j]); v = fminf(fmaxf(v, 0.1f), 1000.0f); }
            else if (MODE == 3) { v = fmaxf(softplus_f(v + bv[j]), RMIN); }
            vals[i][j] = v;
        }
    if (!TRANS) {
#pragma unroll
        for (int i = 0; i < 8; ++i) {
            int row = r0 + i;
            if (row < M) {
                *(float4*)(out + (size_t)row * NO + c0) = *(float4*)(vals[i]);
                if (TN == 8) *(float4*)(out + (size_t)row * NO + c0 + 4) = *(float4*)(vals[i] + 4);
            }
        }
    } else {
        if (r0 + 7 < M) {
#pragma unroll
            for (int j = 0; j < TN; ++j) {
                float c0v[4] = {vals[0][j], vals[1][j], vals[2][j], vals[3][j]};
                float c1v[4] = {vals[4][j], vals[5][j], vals[6][j], vals[7][j]};
                *(float4*)(out + (size_t)(c0 + j) * M + r0) = *(float4*)c0v;
                *(float4*)(out + (size_t)(c0 + j) * M + r0 + 4) = *(float4*)c1v;
            }
        } else {
#pragma unroll
            for (int i = 0; i < 8; ++i) {
                int row = r0 + i;
                if (row < M)
#pragma unroll
                    for (int j = 0; j < TN; ++j) out[(size_t)(c0 + j) * M + row] = vals[i][j];
            }
        }
    }
}

// ---------------- per-node attention logits s,d (vectorized) ----------------
template <int F>
__global__ __launch_bounds__(256) void sd_kernel(const float* __restrict__ xw,
                                                 const float* __restrict__ asrc,
                                                 const float* __restrict__ adst,
                                                 float* __restrict__ s,
                                                 float* __restrict__ d) {
    int wave = threadIdx.x >> 6;
    int lane = threadIdx.x & 63;
    int n = blockIdx.x * 4 + wave;
    if (n >= N_NODES) return;
    float ss, dd;
    if (F == 256) {
        float4 v = *(const float4*)(xw + (size_t)n * 256 + lane * 4);
        float4 as = *(const float4*)(asrc + lane * 4);
        float4 ad = *(const float4*)(adst + lane * 4);
        ss = v.x * as.x + v.y * as.y + v.z * as.z + v.w * as.w;
        dd = v.x * ad.x + v.y * ad.y + v.z * ad.z + v.w * ad.w;
    } else {
        float2 v = *(const float2*)(xw + (size_t)n * 128 + lane * 2);
        float2 as = *(const float2*)(asrc + lane * 2);
        float2 ad = *(const float2*)(adst + lane * 2);
        ss = v.x * as.x + v.y * as.y;
        dd = v.x * ad.x + v.y * ad.y;
    }
#pragma unroll
    for (int off = 8; off > 0; off >>= 1) {
        ss += __shfl_xor(ss, off, 64);
        dd += __shfl_xor(dd, off, 64);
    }
    if ((lane & 15) == 0) {
        int h = lane >> 4;
        s[n * NHEADS + h] = ss;
        d[n * NHEADS + h] = dd;
    }
}

// ---------------- GAT aggregation: one wave per node, lane-specialized head ----------
// Each lane owns head h = lane>>4: computes its own exp weight per edge (1 __expf
// instead of 4 redundant expf in every lane), accumulates den in CSR order.
template <int F>  // 256 -> float4/lane, 128 -> float2/lane
__global__ __launch_bounds__(256) void agg_kernel(const float* __restrict__ xw,
                                                  const float* __restrict__ s,
                                                  const float* __restrict__ d,
                                                  const int* __restrict__ rowptr,
                                                  const int* __restrict__ csr,
                                                  const float* __restrict__ bias,
                                                  float* __restrict__ out) {
    int wave = threadIdx.x >> 6;
    int lane = threadIdx.x & 63;
    int n = blockIdx.x * 4 + wave;
    if (n >= N_NODES) return;
    int h = lane >> 4;
    float dh = d[n * 4 + h];
    // self-loop
    float eself = s[n * 4 + h] + dh;
    eself = eself > 0.f ? eself : SLOPE * eself;
    float wself = __expf(eself);
    float den = wself;

    int beg = rowptr[n], end = rowptr[n + 1];
    if (F == 256) {
        const float4* xw4 = (const float4*)xw;
        float4 v = xw4[(size_t)n * 64 + lane];
        float4 acc = make_float4(wself * v.x, wself * v.y, wself * v.z, wself * v.w);
        int idx = beg;
        for (; idx + 1 < end; idx += 2) {
            int s0 = csr[idx], s1 = csr[idx + 1];
            float e0 = s[s0 * 4 + h] + dh;
            float e1 = s[s1 * 4 + h] + dh;
            e0 = e0 > 0.f ? e0 : SLOPE * e0;
            e1 = e1 > 0.f ? e1 : SLOPE * e1;
            float w0 = __expf(e0);
            float w1 = __expf(e1);
            float4 v0 = xw4[(size_t)s0 * 64 + lane];
            float4 v1 = xw4[(size_t)s1 * 64 + lane];
            den += w0 + w1;
            acc.x += w0 * v0.x; acc.y += w0 * v0.y; acc.z += w0 * v0.z; acc.w += w0 * v0.w;
            acc.x += w1 * v1.x; acc.y += w1 * v1.y; acc.z += w1 * v1.z; acc.w += w1 * v1.w;
        }
        if (idx < end) {
            int s0 = csr[idx];
            float e0 = s[s0 * 4 + h] + dh;
            e0 = e0 > 0.f ? e0 : SLOPE * e0;
            float w0 = __expf(e0);
            float4 v0 = xw4[(size_t)s0 * 64 + lane];
            den += w0;
            acc.x += w0 * v0.x; acc.y += w0 * v0.y; acc.z += w0 * v0.z; acc.w += w0 * v0.w;
        }
        float inv = 1.0f / (den + 1e-16f);
        float4 bv = *(const float4*)(bias + lane * 4);
        float4 o = make_float4(acc.x * inv + bv.x, acc.y * inv + bv.y,
                               acc.z * inv + bv.z, acc.w * inv + bv.w);
        *(float4*)(out + (size_t)n * 256 + lane * 4) = o;
    } else {
        const float2* xw2 = (const float2*)xw;
        float2 v = xw2[(size_t)n * 64 + lane];
        float2 acc = make_float2(wself * v.x, wself * v.y);
        int idx = beg;
        for (; idx + 1 < end; idx += 2) {
            int s0 = csr[idx], s1 = csr[idx + 1];
            float e0 = s[s0 * 4 + h] + dh;
            float e1 = s[s1 * 4 + h] + dh;
            e0 = e0 > 0.f ? e0 : SLOPE * e0;
            e1 = e1 > 0.f ? e1 : SLOPE * e1;
            float w0 = __expf(e0);
            float w1 = __expf(e1);
            float2 v0 = xw2[(size_t)s0 * 64 + lane];
            float2 v1 = xw2[(size_t)s1 * 64 + lane];
            den += w0 + w1;
            acc.x += w0 * v0.x; acc.y += w0 * v0.y;
            acc.x += w1 * v1.x; acc.y += w1 * v1.y;
        }
        if (idx < end) {
            int s0 = csr[idx];
            float e0 = s[s0 * 4 + h] + dh;
            e0 = e0 > 0.f ? e0 : SLOPE * e0;
            float w0 = __expf(e0);
            float2 v0 = xw2[(size_t)s0 * 64 + lane];
            den += w0;
            acc.x += w0 * v0.x; acc.y += w0 * v0.y;
        }
        float inv = 1.0f / (den + 1e-16f);
        float2 bv = *(const float2*)(bias + lane * 2);
        float2 o = make_float2(acc.x * inv + bv.x, acc.y * inv + bv.y);
        *(float2*)(out + (size_t)n * 128 + lane * 2) = o;
    }
}

// ---------------- Weibull reparameterization (vectorized, native transcendentals) ----
__global__ __launch_bounds__(256) void theta_kernel(const float* __restrict__ eps,
                                                    const float* __restrict__ kptr,
                                                    float* __restrict__ lptr,
                                                    float* __restrict__ theta, int ZN) {
    int idx = blockIdx.x * 256 + threadIdx.x;
    int base = idx * 4;
    if (base >= ZN) return;
    float4 k4 = *(const float4*)(kptr + base);
    float4 l4 = *(const float4*)(lptr + base);
    float kk[4] = {k4.x, k4.y, k4.z, k4.w};
    float ll[4] = {l4.x, l4.y, l4.z, l4.w};
    float invk[4], acc[4];
#pragma unroll
    for (int c = 0; c < 4; ++c) {
        invk[c] = 1.0f / kk[c];
        ll[c] = ll[c] / __expf(lgammaf(1.0f + invk[c]));
        acc[c] = 0.0f;
    }
#pragma unroll
    for (int ss = 0; ss < 10; ++ss) {
        float4 u4 = *(const float4*)(eps + (size_t)ss * ZN + base);
        float uu[4] = {u4.x, u4.y, u4.z, u4.w};
#pragma unroll
        for (int c = 0; c < 4; ++c) {
            float w = fmaxf(1.0f - uu[c], RMIN);
            float v = -__logf(w);                       // v >= 0
            acc[c] += __expf(invk[c] * __logf(v));      // v^(1/k); v=0 -> exp(-inf)=0
        }
    }
    float th[4];
#pragma unroll
    for (int c = 0; c < 4; ++c) {
        float t = ll[c] * acc[c] * 0.1f;
        th[c] = fminf(fmaxf(t, RMIN), THETA_MAX);
    }
    *(float4*)(theta + base) = make_float4(th[0], th[1], th[2], th[3]);
    *(float4*)(lptr + base) = make_float4(ll[0], ll[1], ll[2], ll[3]);
}

extern "C" void kernel_launch(void* const* d_in, const int* in_sizes, int n_in,
                              void* d_out, int out_size, void* d_ws, size_t ws_size,
                              hipStream_t stream) {
    const float* x     = (const float*)d_in[0];
    const int*   eidx  = (const int*)d_in[1];
    const float* gatW0 = (const float*)d_in[2];
    const float* asrc0 = (const float*)d_in[3];
    const float* adst0 = (const float*)d_in[4];
    const float* gatb0 = (const float*)d_in[5];
    const float* fcW0  = (const float*)d_in[6];
    const float* fcb0  = (const float*)d_in[7];
    const float* shW0  = (const float*)d_in[8];
    const float* shb0  = (const float*)d_in[9];
    const float* scW0  = (const float*)d_in[10];
    const float* scb0  = (const float*)d_in[11];
    const float* gatW1 = (const float*)d_in[12];
    const float* asrc1 = (const float*)d_in[13];
    const float* adst1 = (const float*)d_in[14];
    const float* gatb1 = (const float*)d_in[15];
    const float* fcW1  = (const float*)d_in[16];
    const float* fcb1  = (const float*)d_in[17];
    const float* shW1  = (const float*)d_in[18];
    const float* shb1  = (const float*)d_in[19];
    const float* scW1  = (const float*)d_in[20];
    const float* scb1  = (const float*)d_in[21];
    const float* eps0  = (const float*)d_in[22];
    const float* eps1  = (const float*)d_in[23];

    const int* e_src = eidx;
    const int* e_dst = eidx + E_EDGES;

    size_t off = 0;
    auto carve = [&](size_t elems) {
        void* p = (char*)d_ws + off;
        off += ((elems * 4 + 255) / 256) * 256;
        return p;
    };
    float* xw0 = (float*)carve(20000u * 256);
    float* h0  = (float*)carve(20000u * 256);
    float* z0  = (float*)carve(20000u * 128);
    float* xw1 = (float*)carve(20000u * 128);
    float* h1  = (float*)carve(20000u * 128);
    float* z1  = (float*)carve(20000u * 64);
    float* s0  = (float*)carve(20000u * 4);
    float* d0  = (float*)carve(20000u * 4);
    float* s1  = (float*)carve(20000u * 4);
    float* d1  = (float*)carve(20000u * 4);
    int* deg    = (int*)carve(20000);
    int* rowptr = (int*)carve(20001);
    int* cursor = (int*)carve(20000);
    int* csr    = (int*)carve(E_EDGES);

    float* out    = (float*)d_out;
    float* theta0 = out;
    float* theta1 = out + 2560000;
    float* k0     = out + 3840000;
    float* k1     = out + 6400000;
    float* l0     = out + 7680000;
    float* l1     = out + 10240000;

    const int M = N_NODES;
    dim3 blk(256);

    // CSR build
    (void)hipMemsetAsync(deg, 0, N_NODES * sizeof(int), stream);
    count_kernel<<<(E_EDGES + 255) / 256, blk, 0, stream>>>(e_dst, deg);
    scan_kernel<<<1, blk, 0, stream>>>(deg, rowptr, cursor);
    scatter_kernel<<<(E_EDGES + 255) / 256, blk, 0, stream>>>(e_src, e_dst, cursor, csr);

    // layer 0
    gemm_big<0, false, 128><<<dim3(157, 2), blk, 0, stream>>>(x, gatW0, nullptr, xw0, M, 256, 256);
    sd_kernel<256><<<5000, blk, 0, stream>>>(xw0, asrc0, adst0, s0, d0);
    agg_kernel<256><<<5000, blk, 0, stream>>>(xw0, s0, d0, rowptr, csr, gatb0, h0);
    gemm_big<1, false, 128><<<dim3(157, 1), blk, 0, stream>>>(h0, fcW0, fcb0, z0, M, 256, 128);

    // layer 1
    gemm_big<0, false, 128><<<dim3(157, 1), blk, 0, stream>>>(h0, gatW1, nullptr, xw1, M, 256, 128);
    sd_kernel<128><<<5000, blk, 0, stream>>>(xw1, asrc1, adst1, s1, d1);
    agg_kernel<128><<<5000, blk, 0, stream>>>(xw1, s1, d1, rowptr, csr, gatb1, h1);
    gemm_big<1, false, 64><<<dim3(157, 1), blk, 0, stream>>>(h1, fcW1, fcb1, z1, M, 128, 64);

    // heads (transposed [z, N] into d_out)
    gemm_big<2, true, 128><<<dim3(157, 1), blk, 0, stream>>>(z0, shW0, shb0, k0, M, 128, 128);
    gemm_big<3, true, 128><<<dim3(157, 1), blk, 0, stream>>>(z0, scW0, scb0, l0, M, 128, 128);
    gemm_big<2, true, 64><<<dim3(157, 1), blk, 0, stream>>>(z1, shW1, shb1, k1, M, 64, 64);
    gemm_big<3, true, 64><<<dim3(157, 1), blk, 0, stream>>>(z1, scW1, scb1, l1, M, 64, 64);

    // reparameterize (finalizes l in-place, writes theta)
    theta_kernel<<<(640000 + 255) / 256, blk, 0, stream>>>(eps0, k0, l0, theta0, 2560000);
    theta_kernel<<<(320000 + 255) / 256, blk, 0, stream>>>(eps1, k1, l1, theta1, 1280000);
}